// Round 3
// baseline (437.680 us; speedup 1.0000x reference)
//
#include <hip/hip_runtime.h>
#include <hip/hip_bf16.h>

// Problem constants (from reference setup_inputs)
#define B_   2
#define N_   512
#define M_   512
#define DQK_ 128    // Dq = Dk = Dv
#define DE_  64     // edge feature dim
#define H_   8      // heads
#define O_   32     // head size
#define OUT_ 128    // output dim
#define DKE_ 192    // Dk + De (key_kernel rows)

typedef unsigned short u16;
typedef unsigned int   u32;

// ---------------------------------------------------------------------------
// Kernel 1: per (b,n): q[h,o] = (query . Wq)/sqrt(32);  qe[h,e] = q . Wk[:,128+e,:]
// grid = B*N blocks, 256 threads
// ---------------------------------------------------------------------------
__global__ __launch_bounds__(256) void k_proj_q(
    const float* __restrict__ query, const float* __restrict__ Wq,
    const float* __restrict__ Wk,
    float* __restrict__ q_out, float* __restrict__ qe_out)
{
    const int idx = blockIdx.x;          // b*N + n
    const int tid = threadIdx.x;
    __shared__ float qs[DQK_];
    __shared__ float qh[H_ * O_];

    if (tid < DQK_) qs[tid] = query[(size_t)idx * DQK_ + tid];
    __syncthreads();

    const int h = tid >> 5, o = tid & 31;
    const float* w = Wq + h * DQK_ * O_ + o;
    float acc = 0.f;
#pragma unroll 8
    for (int i = 0; i < DQK_; ++i) acc += qs[i] * w[i * O_];
    acc *= 0.17677669529663687f;        // 1/sqrt(HEAD_SIZE=32)
    q_out[(size_t)idx * (H_ * O_) + tid] = acc;
    qh[tid] = acc;
    __syncthreads();

    // qe: H*DE = 512 outputs, 2 per thread
    for (int j = tid; j < H_ * DE_; j += 256) {
        const int hh = j >> 6, e = j & 63;
        const float* wk = Wk + hh * (DKE_ * O_) + (DQK_ + e) * O_;
        const float* qrow = qh + hh * O_;
        float a = 0.f;
#pragma unroll
        for (int oo = 0; oo < O_; ++oo) a += qrow[oo] * wk[oo];
        qe_out[(size_t)idx * (H_ * DE_) + j] = a;
    }
}

// ---------------------------------------------------------------------------
// Kernel 2: per (b,m): kp[h,o] = key . Wk[:, :128, :];  v[h,o] = value . Wv
// grid = B*M blocks, 256 threads
// ---------------------------------------------------------------------------
__global__ __launch_bounds__(256) void k_proj_kv(
    const float* __restrict__ key, const float* __restrict__ value,
    const float* __restrict__ Wk, const float* __restrict__ Wv,
    float* __restrict__ kp_out, float* __restrict__ v_out)
{
    const int idx = blockIdx.x;          // b*M + m
    const int tid = threadIdx.x;
    __shared__ float ks[DQK_];
    __shared__ float vs[DQK_];
    if (tid < 128) ks[tid] = key[(size_t)idx * DQK_ + tid];
    else           vs[tid - 128] = value[(size_t)idx * DQK_ + (tid - 128)];
    __syncthreads();

    const int h = tid >> 5, o = tid & 31;
    const float* wk = Wk + h * (DKE_ * O_) + o;
    const float* wv = Wv + h * (DQK_ * O_) + o;
    float ka = 0.f, va = 0.f;
#pragma unroll 8
    for (int i = 0; i < DQK_; ++i) {
        ka += ks[i] * wk[i * O_];
        va += vs[i] * wv[i * O_];
    }
    kp_out[(size_t)idx * (H_ * O_) + tid] = ka;
    v_out [(size_t)idx * (H_ * O_) + tid] = va;
}

// ---------------------------------------------------------------------------
// Kernel 3: per (b,n): logits -> softmax -> attn@v -> projection
// grid = B*N blocks, 256 threads = 8 heads x 32 m-lanes
// ---------------------------------------------------------------------------
__global__ __launch_bounds__(256) void k_attn(
    const float* __restrict__ edge,
    const float* __restrict__ qv, const float* __restrict__ qe,
    const float* __restrict__ kp, const float* __restrict__ vv,
    const float* __restrict__ Wp, const float* __restrict__ bias,
    float* __restrict__ out)
{
    const int idx = blockIdx.x;          // b*N + n
    const int b = idx >> 9;
    const int tid = threadIdx.x;
    const int h = tid >> 5, ml = tid & 31;

    __shared__ float attn_s[H_][M_];     // 16 KB: logits, then attn weights
    __shared__ float mh_s[H_ * O_];      // 1 KB
    __shared__ float part_s[2][OUT_];    // 1 KB

    // qe[h][0..63] and q[h][0..31] into registers (broadcast loads within head group)
    float qe_reg[DE_];
    {
        const float4* qe4 = reinterpret_cast<const float4*>(qe + (size_t)idx * (H_ * DE_) + h * DE_);
#pragma unroll
        for (int i = 0; i < DE_ / 4; ++i) {
            float4 t = qe4[i];
            qe_reg[4*i+0] = t.x; qe_reg[4*i+1] = t.y;
            qe_reg[4*i+2] = t.z; qe_reg[4*i+3] = t.w;
        }
    }
    float q_reg[O_];
    {
        const float4* q4 = reinterpret_cast<const float4*>(qv + (size_t)idx * (H_ * O_) + h * O_);
#pragma unroll
        for (int i = 0; i < O_ / 4; ++i) {
            float4 t = q4[i];
            q_reg[4*i+0] = t.x; q_reg[4*i+1] = t.y;
            q_reg[4*i+2] = t.z; q_reg[4*i+3] = t.w;
        }
    }

    // ---- logits: edge-dot (64) + q.kp (32) per (h, m) ----
    const float* ebase = edge + (size_t)idx * M_ * DE_;
    const float* kpb = kp + (size_t)b * M_ * (H_ * O_) + h * O_;
#pragma unroll 2
    for (int j = 0; j < 16; ++j) {
        const int m = ml + 32 * j;
        const float4* er = reinterpret_cast<const float4*>(ebase + (size_t)m * DE_);
        float acc = 0.f;
#pragma unroll
        for (int w4 = 0; w4 < DE_ / 4; ++w4) {
            float4 t = er[w4];
            acc += qe_reg[4*w4+0] * t.x;
            acc += qe_reg[4*w4+1] * t.y;
            acc += qe_reg[4*w4+2] * t.z;
            acc += qe_reg[4*w4+3] * t.w;
        }
        const float4* kpr = reinterpret_cast<const float4*>(kpb + (size_t)m * (H_ * O_));
#pragma unroll
        for (int i = 0; i < O_ / 4; ++i) {
            float4 t = kpr[i];
            acc += q_reg[4*i+0] * t.x + q_reg[4*i+1] * t.y
                 + q_reg[4*i+2] * t.z + q_reg[4*i+3] * t.w;
        }
        attn_s[h][m] = acc;
    }

    // ---- softmax over m within each head (32-lane group owns one head row) ----
    float mx = -3.4e38f;
#pragma unroll 2
    for (int j = 0; j < 16; ++j) mx = fmaxf(mx, attn_s[h][ml + 32 * j]);
#pragma unroll
    for (int mask = 16; mask >= 1; mask >>= 1) mx = fmaxf(mx, __shfl_xor(mx, mask, 64));

    float sum = 0.f;
#pragma unroll 2
    for (int j = 0; j < 16; ++j) {
        const int m = ml + 32 * j;
        float p = __expf(attn_s[h][m] - mx);
        attn_s[h][m] = p;
        sum += p;
    }
#pragma unroll
    for (int mask = 16; mask >= 1; mask >>= 1) sum += __shfl_xor(sum, mask, 64);
    const float inv = 1.f / sum;
#pragma unroll 2
    for (int j = 0; j < 16; ++j) attn_s[h][ml + 32 * j] *= inv;
    __syncthreads();

    // ---- mh[h][o] = sum_m attn[h][m] * v[b,m,h,o] ----
    // thread = (h, sub(2b), og(3b)): og covers 4 o's via float4, sub strides m by 4
    {
        const int sub = (tid >> 3) & 3, og = tid & 7;
        float4 acc4 = make_float4(0.f, 0.f, 0.f, 0.f);
        const float* vb = vv + (size_t)b * M_ * (H_ * O_) + h * O_ + og * 4;
        for (int m = sub; m < M_; m += 4) {
            const float a = attn_s[h][m];
            float4 t = *reinterpret_cast<const float4*>(vb + (size_t)m * (H_ * O_));
            acc4.x += a * t.x; acc4.y += a * t.y;
            acc4.z += a * t.z; acc4.w += a * t.w;
        }
#pragma unroll
        for (int mask = 8; mask <= 16; mask <<= 1) {
            acc4.x += __shfl_xor(acc4.x, mask, 64);
            acc4.y += __shfl_xor(acc4.y, mask, 64);
            acc4.z += __shfl_xor(acc4.z, mask, 64);
            acc4.w += __shfl_xor(acc4.w, mask, 64);
        }
        if (sub == 0) {
            mh_s[h * O_ + og * 4 + 0] = acc4.x;
            mh_s[h * O_ + og * 4 + 1] = acc4.y;
            mh_s[h * O_ + og * 4 + 2] = acc4.z;
            mh_s[h * O_ + og * 4 + 3] = acc4.w;
        }
    }
    __syncthreads();

    // ---- out[c] = bias[c] + sum_{h,o} mh[h*32+o] * Wp[(h*32+o)*128 + c] ----
    {
        const int half = tid >> 7;       // 0/1: split the 256-term sum
        const int c = tid & 127;
        float acc = 0.f;
        const int j0 = half * 128;
#pragma unroll 8
        for (int jj = 0; jj < 128; ++jj)
            acc += mh_s[j0 + jj] * Wp[(size_t)(j0 + jj) * OUT_ + c];
        part_s[half][c] = acc;
    }
    __syncthreads();
    if (tid < OUT_) {
        out[(size_t)idx * OUT_ + tid] = part_s[0][tid] + part_s[1][tid] + bias[tid];
    }
}

// ---------------------------------------------------------------------------
extern "C" void kernel_launch(void* const* d_in, const int* in_sizes, int n_in,
                              void* d_out, int out_size, void* d_ws, size_t ws_size,
                              hipStream_t stream)
{
    const float* query = (const float*)d_in[0];   // [B,N,128]
    const float* key   = (const float*)d_in[1];   // [B,M,128]
    const float* value = (const float*)d_in[2];   // [B,M,128]
    const float* edge  = (const float*)d_in[3];   // [B,N,M,64]
    const float* Wq    = (const float*)d_in[4];   // [8,128,32]
    const float* Wk    = (const float*)d_in[5];   // [8,192,32]
    const float* Wv    = (const float*)d_in[6];   // [8,128,32]
    const float* Wp    = (const float*)d_in[7];   // [8,32,128]
    const float* bias  = (const float*)d_in[8];   // [128]
    float* out = (float*)d_out;                   // [B,N,128] fp32 (reference output dtype)

    float* ws   = (float*)d_ws;
    float* q_ws  = ws;                 // B*N*H*O   = 262144
    float* qe_ws = ws + 262144;        // B*N*H*DE  = 524288
    float* kp_ws = ws + 786432;        // B*M*H*O   = 262144
    float* v_ws  = ws + 1048576;       // B*M*H*O   = 262144  (total 5.24 MB)

    k_proj_q <<<B_ * N_, 256, 0, stream>>>(query, Wq, Wk, q_ws, qe_ws);
    k_proj_kv<<<B_ * M_, 256, 0, stream>>>(key, value, Wk, Wv, kp_ws, v_ws);
    k_attn   <<<B_ * N_, 256, 0, stream>>>(edge, q_ws, qe_ws, kp_ws, v_ws, Wp, bias, out);
}

// Round 4
// 296.987 us; speedup vs baseline: 1.4737x; 1.4737x over previous
//
#include <hip/hip_runtime.h>

// Problem constants
#define B_   2
#define N_   512
#define M_   512
#define D_   128    // Dq = Dk = Dv
#define DE_  64
#define H_   8
#define O_   32
#define OUT_ 128
#define DKE_ 192    // Dk + De
#define MP_  516    // padded M for attn_s (516 mod 32 = 4 -> bank-clean)

// ---------------------------------------------------------------------------
// Kernel A: per 8 (b,n) rows: q̂ = (query@Wq)/sqrt(32) (kept in LDS),
//           qE[row][h*192+j] = sum_o q̂[row][h,o] * Wk[h,j,o]   (j = 0..191)
// grid = 128 blocks x 256 threads
// ---------------------------------------------------------------------------
__global__ __launch_bounds__(256) void k_proj_a(
    const float* __restrict__ query, const float* __restrict__ Wq,
    const float* __restrict__ Wk, float* __restrict__ qE)
{
    const int r0 = blockIdx.x * 8;
    const int t  = threadIdx.x;
    __shared__ float Xs[8][D_];        // 4 KB
    __shared__ float qh[8][H_ * O_];   // 8 KB

    // stage 8 query rows (4 KB) fully coalesced: 256 threads x float4
    reinterpret_cast<float4*>(&Xs[0][0])[t] =
        reinterpret_cast<const float4*>(query + (size_t)r0 * D_)[t];
    __syncthreads();

    // q GEMM: thread = col c = h*32+o, 8 row-accumulators
    {
        float acc[8] = {0,0,0,0,0,0,0,0};
        const float* wcol = Wq + (t >> 5) * (D_ * O_) + (t & 31);
        for (int k = 0; k < D_; k += 4) {
            const float w0 = wcol[(k+0) * O_];
            const float w1 = wcol[(k+1) * O_];
            const float w2 = wcol[(k+2) * O_];
            const float w3 = wcol[(k+3) * O_];
#pragma unroll
            for (int r = 0; r < 8; ++r) {
                const float4 x = *reinterpret_cast<const float4*>(&Xs[r][k]);
                acc[r] += x.x * w0 + x.y * w1 + x.z * w2 + x.w * w3;
            }
        }
#pragma unroll
        for (int r = 0; r < 8; ++r) qh[r][t] = acc[r] * 0.17677669529663687f;
    }
    __syncthreads();

    // qE: 1536 cols (hj = h*192+j), 6 per thread; Wk flat index = hj*32+o
    for (int s = 0; s < 6; ++s) {
        const int hj = t + 256 * s;
        const int h  = hj / DKE_;
        float w[O_];
#pragma unroll
        for (int i = 0; i < O_ / 4; ++i) {
            const float4 x = reinterpret_cast<const float4*>(Wk + (size_t)hj * O_)[i];
            w[4*i] = x.x; w[4*i+1] = x.y; w[4*i+2] = x.z; w[4*i+3] = x.w;
        }
#pragma unroll
        for (int r = 0; r < 8; ++r) {
            const float* qrow = &qh[r][h * O_];
            float a = 0.f;
#pragma unroll
            for (int i = 0; i < O_ / 4; ++i) {
                const float4 qx = *reinterpret_cast<const float4*>(qrow + 4*i);
                a += qx.x * w[4*i] + qx.y * w[4*i+1] + qx.z * w[4*i+2] + qx.w * w[4*i+3];
            }
            qE[(size_t)(r0 + r) * (H_ * DKE_) + hj] = a;
        }
    }
}

// ---------------------------------------------------------------------------
// Kernel V: per 8 (b,m) rows: v[row][h*32+o] = value . Wv
// grid = 128 blocks x 256 threads
// ---------------------------------------------------------------------------
__global__ __launch_bounds__(256) void k_proj_v(
    const float* __restrict__ value, const float* __restrict__ Wv,
    float* __restrict__ vo)
{
    const int r0 = blockIdx.x * 8;
    const int t  = threadIdx.x;
    __shared__ float Xs[8][D_];
    reinterpret_cast<float4*>(&Xs[0][0])[t] =
        reinterpret_cast<const float4*>(value + (size_t)r0 * D_)[t];
    __syncthreads();

    float acc[8] = {0,0,0,0,0,0,0,0};
    const float* wcol = Wv + (t >> 5) * (D_ * O_) + (t & 31);
    for (int k = 0; k < D_; k += 4) {
        const float w0 = wcol[(k+0) * O_];
        const float w1 = wcol[(k+1) * O_];
        const float w2 = wcol[(k+2) * O_];
        const float w3 = wcol[(k+3) * O_];
#pragma unroll
        for (int r = 0; r < 8; ++r) {
            const float4 x = *reinterpret_cast<const float4*>(&Xs[r][k]);
            acc[r] += x.x * w0 + x.y * w1 + x.z * w2 + x.w * w3;
        }
    }
#pragma unroll
    for (int r = 0; r < 8; ++r) vo[(size_t)(r0 + r) * (H_ * O_) + t] = acc[r];
}

// ---------------------------------------------------------------------------
// Kernel 3: per (b,n): logits (all heads per lane-group, coalesced edge/key),
//           softmax, attn@v, projection.
// grid = 1024 blocks x 256 threads (4 waves; wave = 4 groups of 16 lanes)
// ---------------------------------------------------------------------------
__global__ __launch_bounds__(256) void k_attn(
    const float* __restrict__ key, const float* __restrict__ edge,
    const float* __restrict__ qE, const float* __restrict__ vv,
    const float* __restrict__ Wp, const float* __restrict__ bias,
    float* __restrict__ out)
{
    const int idx = blockIdx.x;          // b*N + n
    const int b   = idx >> 9;
    const int t   = threadIdx.x;
    const int lane = t & 63;
    const int wv   = t >> 6;             // wave 0..3
    const int grp  = lane >> 4;          // row group 0..3
    const int el   = lane & 15;

    __shared__ float attn_s[H_][MP_];    // 16.5 KB
    __shared__ float mh_s[H_ * O_];      // 1 KB
    __shared__ float part_s[2][OUT_];    // 1 KB

    // qE fragments: all 8 heads, 3 chunks of 4 (j = p*64 + el*4) -> 96 VGPRs
    float qf[8][12];
    {
        const float* base = qE + (size_t)idx * (H_ * DKE_);
#pragma unroll
        for (int h = 0; h < 8; ++h) {
#pragma unroll
            for (int p = 0; p < 3; ++p) {
                const float4 x = *reinterpret_cast<const float4*>(
                    base + h * DKE_ + p * 64 + el * 4);
                qf[h][4*p]   = x.x; qf[h][4*p+1] = x.y;
                qf[h][4*p+2] = x.z; qf[h][4*p+3] = x.w;
            }
        }
    }

    const float* keyb = key  + (size_t)b   * M_ * D_;
    const float* eb   = edge + (size_t)idx * M_ * DE_;
    const int sel3 = (el >> 3) & 1, sel2 = (el >> 2) & 1, sel1 = (el >> 1) & 1;

    // ---- logits: each 16-lane group produces all 8 heads for one m per iter
    for (int it = 0; it < 32; ++it) {
        const int m = it * 16 + wv * 4 + grp;
        const float4 k0 = *reinterpret_cast<const float4*>(keyb + (size_t)m * D_ + el * 4);
        const float4 k1 = *reinterpret_cast<const float4*>(keyb + (size_t)m * D_ + 64 + el * 4);
        const float4 e0 = *reinterpret_cast<const float4*>(eb + (size_t)m * DE_ + el * 4);
        float a[8];
#pragma unroll
        for (int h = 0; h < 8; ++h) {
            a[h] = qf[h][0]*k0.x + qf[h][1]*k0.y + qf[h][2]*k0.z + qf[h][3]*k0.w
                 + qf[h][4]*k1.x + qf[h][5]*k1.y + qf[h][6]*k1.z + qf[h][7]*k1.w
                 + qf[h][8]*e0.x + qf[h][9]*e0.y + qf[h][10]*e0.z + qf[h][11]*e0.w;
        }
        // transposed butterfly over the 16-lane group:
        // after step k, each lane carries the heads selected by its high lane bits;
        // final: lanes 2h,2h+1 hold head h summed over all 16 lanes.
        float b4[4];
#pragma unroll
        for (int q2 = 0; q2 < 4; ++q2) {
            const float tA = __shfl_xor(a[q2], 8, 16);
            const float tB = __shfl_xor(a[q2 + 4], 8, 16);
            b4[q2] = sel3 ? (a[q2 + 4] + tB) : (a[q2] + tA);
        }
        float c2[2];
#pragma unroll
        for (int q2 = 0; q2 < 2; ++q2) {
            const float tA = __shfl_xor(b4[q2], 4, 16);
            const float tB = __shfl_xor(b4[q2 + 2], 4, 16);
            c2[q2] = sel2 ? (b4[q2 + 2] + tB) : (b4[q2] + tA);
        }
        const float tA = __shfl_xor(c2[0], 2, 16);
        const float tB = __shfl_xor(c2[1], 2, 16);
        float d = sel1 ? (c2[1] + tB) : (c2[0] + tA);
        d += __shfl_xor(d, 1, 16);
        if ((el & 1) == 0) attn_s[(el >> 1) & 7][m] = d;
    }
    __syncthreads();

    // ---- softmax over m per head (half-wave owns one head row) ----
    {
        const int h = t >> 5, ml = t & 31;
        float mx = -3.4e38f;
#pragma unroll 2
        for (int j = 0; j < 16; ++j) mx = fmaxf(mx, attn_s[h][ml + 32 * j]);
#pragma unroll
        for (int mask = 16; mask >= 1; mask >>= 1) mx = fmaxf(mx, __shfl_xor(mx, mask, 64));
        float sum = 0.f;
#pragma unroll 2
        for (int j = 0; j < 16; ++j) {
            const int m = ml + 32 * j;
            const float p = __expf(attn_s[h][m] - mx);
            attn_s[h][m] = p;
            sum += p;
        }
#pragma unroll
        for (int mask = 16; mask >= 1; mask >>= 1) sum += __shfl_xor(sum, mask, 64);
        const float inv = 1.f / sum;
#pragma unroll 2
        for (int j = 0; j < 16; ++j) attn_s[h][ml + 32 * j] *= inv;
    }
    __syncthreads();

    // ---- mh[h][o]: thread = (h,o) = t, 4 independent accumulators ----
    {
        const int hh = t >> 5;
        const float* vb = vv + (size_t)b * M_ * (H_ * O_) + t;
        float a0 = 0.f, a1 = 0.f, a2 = 0.f, a3 = 0.f;
        for (int m = 0; m < M_; m += 4) {
            const float4 aw = *reinterpret_cast<const float4*>(&attn_s[hh][m]);
            a0 += aw.x * vb[(size_t)(m + 0) * 256];
            a1 += aw.y * vb[(size_t)(m + 1) * 256];
            a2 += aw.z * vb[(size_t)(m + 2) * 256];
            a3 += aw.w * vb[(size_t)(m + 3) * 256];
        }
        mh_s[t] = (a0 + a1) + (a2 + a3);
    }
    __syncthreads();

    // ---- out[c] = bias[c] + sum_j mh[j] * Wp[j*128 + c] ----
    {
        const int half = t >> 7;
        const int c = t & 127;
        float acc = 0.f;
        const int j0 = half * 128;
#pragma unroll 8
        for (int jj = 0; jj < 128; ++jj)
            acc += mh_s[j0 + jj] * Wp[(size_t)(j0 + jj) * OUT_ + c];
        part_s[half][c] = acc;
    }
    __syncthreads();
    if (t < OUT_)
        out[(size_t)idx * OUT_ + t] = part_s[0][t] + part_s[1][t] + bias[t];
}

// ---------------------------------------------------------------------------
extern "C" void kernel_launch(void* const* d_in, const int* in_sizes, int n_in,
                              void* d_out, int out_size, void* d_ws, size_t ws_size,
                              hipStream_t stream)
{
    const float* query = (const float*)d_in[0];   // [B,N,128]
    const float* key   = (const float*)d_in[1];   // [B,M,128]
    const float* value = (const float*)d_in[2];   // [B,M,128]
    const float* edge  = (const float*)d_in[3];   // [B,N,M,64]
    const float* Wq    = (const float*)d_in[4];   // [8,128,32]
    const float* Wk    = (const float*)d_in[5];   // [8,192,32]
    const float* Wv    = (const float*)d_in[6];   // [8,128,32]
    const float* Wp    = (const float*)d_in[7];   // [8,32,128]
    const float* bias  = (const float*)d_in[8];   // [128]
    float* out = (float*)d_out;                   // [B,N,128] fp32

    float* ws    = (float*)d_ws;
    float* qE_ws = ws;                        // B*N*H*192 = 1,572,864 floats (6.3 MB)
    float* v_ws  = ws + (size_t)B_ * N_ * H_ * DKE_;   // B*M*256 = 262,144 floats (1 MB)

    k_proj_a<<<(B_ * N_) / 8, 256, 0, stream>>>(query, Wq, Wk, qE_ws);
    k_proj_v<<<(B_ * M_) / 8, 256, 0, stream>>>(value, Wv, v_ws);
    k_attn  <<<B_ * N_, 256, 0, stream>>>(key, edge, qE_ws, v_ws, Wp, bias, out);
}

// Round 5
// 289.785 us; speedup vs baseline: 1.5104x; 1.0249x over previous
//
#include <hip/hip_runtime.h>
#include <hip/hip_bf16.h>

// Problem constants
#define B_   2
#define N_   512
#define M_   512
#define D_   128    // Dq = Dk = Dv
#define DE_  64
#define H_   8
#define O_   32
#define OUT_ 128
#define DKE_ 192    // Dk + De
#define MP_  516    // padded M for attn_s rows
#define BTP_ 200    // padded B-tile row (ushorts): 400 B stride, 16B-aligned, 2-way banks

typedef unsigned short u16;
typedef unsigned int   u32;
typedef short bf16x8 __attribute__((ext_vector_type(8)));
typedef float floatx4 __attribute__((ext_vector_type(4)));

__device__ __forceinline__ u32 pk2bf(float a, float b) {
    __hip_bfloat162 h = __float22bfloat162_rn(make_float2(a, b));
    return *reinterpret_cast<u32*>(&h);
}
__device__ __forceinline__ u16 f2bf(float a) {
    __hip_bfloat16 h = __float2bfloat16(a);
    return *reinterpret_cast<u16*>(&h);
}

// ---------------------------------------------------------------------------
// Kernel A: per 8 (b,n) rows: q̂ = (query@Wq)/sqrt(32) (LDS),
//           qE[row][h*192+j] = sum_o q̂[row][h,o]*Wk[h,j,o]  -> bf16
// grid = 128 x 256
// ---------------------------------------------------------------------------
__global__ __launch_bounds__(256) void k_proj_a(
    const float* __restrict__ query, const float* __restrict__ Wq,
    const float* __restrict__ Wk, u16* __restrict__ qE)
{
    const int r0 = blockIdx.x * 8;
    const int t  = threadIdx.x;
    __shared__ float Xs[8][D_];
    __shared__ float qh[8][H_ * O_];

    reinterpret_cast<float4*>(&Xs[0][0])[t] =
        reinterpret_cast<const float4*>(query + (size_t)r0 * D_)[t];
    __syncthreads();

    {
        float acc[8] = {0,0,0,0,0,0,0,0};
        const float* wcol = Wq + (t >> 5) * (D_ * O_) + (t & 31);
        for (int k = 0; k < D_; k += 4) {
            const float w0 = wcol[(k+0) * O_];
            const float w1 = wcol[(k+1) * O_];
            const float w2 = wcol[(k+2) * O_];
            const float w3 = wcol[(k+3) * O_];
#pragma unroll
            for (int r = 0; r < 8; ++r) {
                const float4 x = *reinterpret_cast<const float4*>(&Xs[r][k]);
                acc[r] += x.x * w0 + x.y * w1 + x.z * w2 + x.w * w3;
            }
        }
#pragma unroll
        for (int r = 0; r < 8; ++r) qh[r][t] = acc[r] * 0.17677669529663687f;
    }
    __syncthreads();

    for (int s = 0; s < 6; ++s) {
        const int hj = t + 256 * s;
        const int h  = hj / DKE_;
        float w[O_];
#pragma unroll
        for (int i = 0; i < O_ / 4; ++i) {
            const float4 x = reinterpret_cast<const float4*>(Wk + (size_t)hj * O_)[i];
            w[4*i] = x.x; w[4*i+1] = x.y; w[4*i+2] = x.z; w[4*i+3] = x.w;
        }
#pragma unroll
        for (int r = 0; r < 8; ++r) {
            const float* qrow = &qh[r][h * O_];
            float a = 0.f;
#pragma unroll
            for (int i = 0; i < O_ / 4; ++i) {
                const float4 qx = *reinterpret_cast<const float4*>(qrow + 4*i);
                a += qx.x * w[4*i] + qx.y * w[4*i+1] + qx.z * w[4*i+2] + qx.w * w[4*i+3];
            }
            qE[(size_t)(r0 + r) * (H_ * DKE_) + hj] = f2bf(a);
        }
    }
}

// ---------------------------------------------------------------------------
// Kernel V: per 8 (b,m) rows: v[row][h*32+o] = value . Wv   (fp32)
// grid = 128 x 256
// ---------------------------------------------------------------------------
__global__ __launch_bounds__(256) void k_proj_v(
    const float* __restrict__ value, const float* __restrict__ Wv,
    float* __restrict__ vo)
{
    const int r0 = blockIdx.x * 8;
    const int t  = threadIdx.x;
    __shared__ float Xs[8][D_];
    reinterpret_cast<float4*>(&Xs[0][0])[t] =
        reinterpret_cast<const float4*>(value + (size_t)r0 * D_)[t];
    __syncthreads();

    float acc[8] = {0,0,0,0,0,0,0,0};
    const float* wcol = Wv + (t >> 5) * (D_ * O_) + (t & 31);
    for (int k = 0; k < D_; k += 4) {
        const float w0 = wcol[(k+0) * O_];
        const float w1 = wcol[(k+1) * O_];
        const float w2 = wcol[(k+2) * O_];
        const float w3 = wcol[(k+3) * O_];
#pragma unroll
        for (int r = 0; r < 8; ++r) {
            const float4 x = *reinterpret_cast<const float4*>(&Xs[r][k]);
            acc[r] += x.x * w0 + x.y * w1 + x.z * w2 + x.w * w3;
        }
    }
#pragma unroll
    for (int r = 0; r < 8; ++r) vo[(size_t)(r0 + r) * (H_ * O_) + t] = acc[r];
}

// ---------------------------------------------------------------------------
// Kernel 3: per (b,n). Logits via MFMA 16x16x32 bf16 (A = qE[16rows x 192],
// rows 8..15 zero; B = cat(key,edge) tiles, fp32->bf16 staged per wave,
// double-buffered global loads). Then softmax, vector PV, projection.
// grid = 1024 x 256 (4 waves; each wave owns 8 of 32 m-tiles)
// ---------------------------------------------------------------------------
__global__ __launch_bounds__(256, 3) void k_attn(
    const float* __restrict__ key, const float* __restrict__ edge,
    const u16* __restrict__ qE, const float* __restrict__ vv,
    const float* __restrict__ Wp, const float* __restrict__ bias,
    float* __restrict__ out)
{
    const int idx  = blockIdx.x;          // b*N + n
    const int b    = idx >> 9;
    const int t    = threadIdx.x;
    const int lane = t & 63;
    const int wv   = t >> 6;

    __shared__ __attribute__((aligned(16))) u16 Bt[4][16][BTP_];   // 25.6 KB
    __shared__ __attribute__((aligned(16))) float attn_s[H_][MP_]; // 16.5 KB
    __shared__ float mh_s[H_ * O_];
    __shared__ float part_s[2][OUT_];

    // ---- A fragments: lane l holds qE[row=l&15][kk*32 + (l>>4)*8 + 0..7] ----
    bf16x8 afr[6];
    {
        const int ar = lane & 15, aq = lane >> 4;
        if (ar < 8) {
            const u16* ab = qE + (size_t)idx * (H_ * DKE_) + ar * DKE_;
#pragma unroll
            for (int kk = 0; kk < 6; ++kk)
                afr[kk] = *reinterpret_cast<const bf16x8*>(ab + kk * 32 + aq * 8);
        } else {
#pragma unroll
            for (int kk = 0; kk < 6; ++kk) afr[kk] = bf16x8{0,0,0,0,0,0,0,0};
        }
    }

    const float* keyb = key  + (size_t)b   * M_ * D_;
    const float* eb   = edge + (size_t)idx * M_ * DE_;
    const int r  = lane >> 2;   // staging row 0..15
    const int s4 = lane & 3;    // staging segment 0..3

    // double-buffered staging registers (48 floats per buffer)
    float4 kreg[2][8], ereg[2][4];

    // prologue: load tile (wv)
    {
        const int m0 = wv * 16;
        const float* kr = keyb + (size_t)(m0 + r) * D_ + s4 * 32;
        const float* er = eb   + (size_t)(m0 + r) * DE_ + s4 * 16;
#pragma unroll
        for (int i = 0; i < 8; ++i) kreg[0][i] = *reinterpret_cast<const float4*>(kr + i * 4);
#pragma unroll
        for (int i = 0; i < 4; ++i) ereg[0][i] = *reinterpret_cast<const float4*>(er + i * 4);
    }

    int buf = 0;
    for (int it = 0; it < 8; ++it) {
        const int tl = it * 4 + wv;
        // prefetch next tile into the other buffer
        if (it < 7) {
            const int m0 = (tl + 4) * 16;
            const float* kr = keyb + (size_t)(m0 + r) * D_ + s4 * 32;
            const float* er = eb   + (size_t)(m0 + r) * DE_ + s4 * 16;
#pragma unroll
            for (int i = 0; i < 8; ++i) kreg[buf^1][i] = *reinterpret_cast<const float4*>(kr + i * 4);
#pragma unroll
            for (int i = 0; i < 4; ++i) ereg[buf^1][i] = *reinterpret_cast<const float4*>(er + i * 4);
        }
        // stage current tile: fp32 -> bf16 -> LDS (row r, 2-way banks = free)
        {
            u16* dst = &Bt[wv][r][0];
#pragma unroll
            for (int i = 0; i < 8; ++i) {
                uint2 p;
                p.x = pk2bf(kreg[buf][i].x, kreg[buf][i].y);
                p.y = pk2bf(kreg[buf][i].z, kreg[buf][i].w);
                *reinterpret_cast<uint2*>(dst + s4 * 32 + i * 4) = p;
            }
#pragma unroll
            for (int i = 0; i < 4; ++i) {
                uint2 p;
                p.x = pk2bf(ereg[buf][i].x, ereg[buf][i].y);
                p.y = pk2bf(ereg[buf][i].z, ereg[buf][i].w);
                *reinterpret_cast<uint2*>(dst + D_ + s4 * 16 + i * 4) = p;
            }
        }
        // fragments + MFMA (same-wave DS ordering guarantees read-after-write)
        {
            const int br = lane & 15, q = lane >> 4;
            floatx4 acc = {0.f, 0.f, 0.f, 0.f};
#pragma unroll
            for (int kk = 0; kk < 6; ++kk) {
                const bf16x8 bfr = *reinterpret_cast<const bf16x8*>(&Bt[wv][br][kk * 32 + q * 8]);
                acc = __builtin_amdgcn_mfma_f32_16x16x32_bf16(afr[kk], bfr, acc, 0, 0, 0);
            }
            if (q < 2) {
#pragma unroll
                for (int i = 0; i < 4; ++i)
                    attn_s[q * 4 + i][tl * 16 + br] = acc[i];
            }
        }
        buf ^= 1;
    }
    __syncthreads();

    // ---- softmax over m per head (32 lanes own one head row) ----
    {
        const int h = t >> 5, ml = t & 31;
        float mx = -3.4e38f;
#pragma unroll 2
        for (int j = 0; j < 16; ++j) mx = fmaxf(mx, attn_s[h][ml + 32 * j]);
#pragma unroll
        for (int mask = 16; mask >= 1; mask >>= 1) mx = fmaxf(mx, __shfl_xor(mx, mask, 64));
        float sum = 0.f;
#pragma unroll 2
        for (int j = 0; j < 16; ++j) {
            const int m = ml + 32 * j;
            const float p = __expf(attn_s[h][m] - mx);
            attn_s[h][m] = p;
            sum += p;
        }
#pragma unroll
        for (int mask = 16; mask >= 1; mask >>= 1) sum += __shfl_xor(sum, mask, 64);
        const float inv = 1.f / sum;
#pragma unroll 2
        for (int j = 0; j < 16; ++j) attn_s[h][ml + 32 * j] *= inv;
    }
    __syncthreads();

    // ---- mh[h][o]: thread = (h,o) = t, 4 independent accumulators ----
    {
        const int hh = t >> 5;
        const float* vb = vv + (size_t)b * M_ * (H_ * O_) + t;
        float a0 = 0.f, a1 = 0.f, a2 = 0.f, a3 = 0.f;
        for (int m = 0; m < M_; m += 4) {
            const float4 aw = *reinterpret_cast<const float4*>(&attn_s[hh][m]);
            a0 += aw.x * vb[(size_t)(m + 0) * 256];
            a1 += aw.y * vb[(size_t)(m + 1) * 256];
            a2 += aw.z * vb[(size_t)(m + 2) * 256];
            a3 += aw.w * vb[(size_t)(m + 3) * 256];
        }
        mh_s[t] = (a0 + a1) + (a2 + a3);
    }
    __syncthreads();

    // ---- out[c] = bias[c] + sum_j mh[j] * Wp[j*128 + c] ----
    {
        const int half = t >> 7;
        const int c = t & 127;
        float acc = 0.f;
        const int j0 = half * 128;
#pragma unroll 8
        for (int jj = 0; jj < 128; ++jj)
            acc += mh_s[j0 + jj] * Wp[(size_t)(j0 + jj) * OUT_ + c];
        part_s[half][c] = acc;
    }
    __syncthreads();
    if (t < OUT_)
        out[(size_t)idx * OUT_ + t] = part_s[0][t] + part_s[1][t] + bias[t];
}

// ---------------------------------------------------------------------------
extern "C" void kernel_launch(void* const* d_in, const int* in_sizes, int n_in,
                              void* d_out, int out_size, void* d_ws, size_t ws_size,
                              hipStream_t stream)
{
    const float* query = (const float*)d_in[0];   // [B,N,128]
    const float* key   = (const float*)d_in[1];   // [B,M,128]
    const float* value = (const float*)d_in[2];   // [B,M,128]
    const float* edge  = (const float*)d_in[3];   // [B,N,M,64]
    const float* Wq    = (const float*)d_in[4];   // [8,128,32]
    const float* Wk    = (const float*)d_in[5];   // [8,192,32]
    const float* Wv    = (const float*)d_in[6];   // [8,128,32]
    const float* Wp    = (const float*)d_in[7];   // [8,32,128]
    const float* bias  = (const float*)d_in[8];   // [128]
    float* out = (float*)d_out;                   // [B,N,128] fp32

    u16*   qE_ws = (u16*)d_ws;                                        // 1024*1536 bf16 = 3.1 MB
    float* v_ws  = (float*)((char*)d_ws + (size_t)B_*N_*H_*DKE_*2);   // 1 MB fp32

    k_proj_a<<<(B_ * N_) / 8, 256, 0, stream>>>(query, Wq, Wk, qE_ws);
    k_proj_v<<<(B_ * M_) / 8, 256, 0, stream>>>(value, Wv, v_ws);
    k_attn  <<<B_ * N_, 256, 0, stream>>>(key, edge, qE_ws, v_ws, Wp, bias, out);
}

// Round 6
// 276.135 us; speedup vs baseline: 1.5850x; 1.0494x over previous
//
#include <hip/hip_runtime.h>
#include <hip/hip_bf16.h>

// Problem constants
#define B_   2
#define N_   512
#define M_   512
#define D_   128    // Dq = Dk = Dv
#define DE_  64
#define H_   8
#define O_   32
#define OUT_ 128
#define DKE_ 192    // Dk + De
#define MP_  516    // padded M for attn_s rows

typedef unsigned short u16;
typedef unsigned int   u32;
typedef short bf16x8 __attribute__((ext_vector_type(8)));
typedef float floatx4 __attribute__((ext_vector_type(4)));

__device__ __forceinline__ u32 pk2bf(float a, float b) {
    __hip_bfloat162 h = __float22bfloat162_rn(make_float2(a, b));
    return *reinterpret_cast<u32*>(&h);
}
__device__ __forceinline__ u16 f2bf(float a) {
    __hip_bfloat16 h = __float2bfloat16(a);
    return *reinterpret_cast<u16*>(&h);
}
__device__ __forceinline__ float bf2f(u16 x) {
    return __uint_as_float(((u32)x) << 16);
}
// pack 8 fp32 (two float4) -> bf16x8 fragment
__device__ __forceinline__ bf16x8 cvt8(const float4 a, const float4 b) {
    union { u32 u[4]; bf16x8 v; } r;
    r.u[0] = pk2bf(a.x, a.y); r.u[1] = pk2bf(a.z, a.w);
    r.u[2] = pk2bf(b.x, b.y); r.u[3] = pk2bf(b.z, b.w);
    return r.v;
}

// ---------------------------------------------------------------------------
// Merged projection kernel, grid = 256 x 256 threads.
// Blocks 0..127   : per 8 (b,n) rows -> qE bf16 [row][h*192+j]
// Blocks 128..255 : per 8 (b,m) rows -> vvT bf16 [b][col=h*32+o][m]
// ---------------------------------------------------------------------------
__global__ __launch_bounds__(256) void k_proj(
    const float* __restrict__ query, const float* __restrict__ Wq,
    const float* __restrict__ Wk,
    const float* __restrict__ value, const float* __restrict__ Wv,
    u16* __restrict__ qE, u16* __restrict__ vvT)
{
    const int t = threadIdx.x;
    __shared__ float Xs[8][D_];
    __shared__ float qh[8][H_ * O_];

    if (blockIdx.x < 128) {
        const int r0 = blockIdx.x * 8;
        reinterpret_cast<float4*>(&Xs[0][0])[t] =
            reinterpret_cast<const float4*>(query + (size_t)r0 * D_)[t];
        __syncthreads();
        {
            float acc[8] = {0,0,0,0,0,0,0,0};
            const float* wcol = Wq + (t >> 5) * (D_ * O_) + (t & 31);
            for (int k = 0; k < D_; k += 4) {
                const float w0 = wcol[(k+0) * O_];
                const float w1 = wcol[(k+1) * O_];
                const float w2 = wcol[(k+2) * O_];
                const float w3 = wcol[(k+3) * O_];
#pragma unroll
                for (int r = 0; r < 8; ++r) {
                    const float4 x = *reinterpret_cast<const float4*>(&Xs[r][k]);
                    acc[r] += x.x * w0 + x.y * w1 + x.z * w2 + x.w * w3;
                }
            }
#pragma unroll
            for (int r = 0; r < 8; ++r) qh[r][t] = acc[r] * 0.17677669529663687f;
        }
        __syncthreads();

        for (int s = 0; s < 6; ++s) {
            const int hj = t + 256 * s;
            const int h  = hj / DKE_;
            float w[O_];
#pragma unroll
            for (int i = 0; i < O_ / 4; ++i) {
                const float4 x = reinterpret_cast<const float4*>(Wk + (size_t)hj * O_)[i];
                w[4*i] = x.x; w[4*i+1] = x.y; w[4*i+2] = x.z; w[4*i+3] = x.w;
            }
#pragma unroll
            for (int r = 0; r < 8; ++r) {
                const float* qrow = &qh[r][h * O_];
                float a = 0.f;
#pragma unroll
                for (int i = 0; i < O_ / 4; ++i) {
                    const float4 qx = *reinterpret_cast<const float4*>(qrow + 4*i);
                    a += qx.x * w[4*i] + qx.y * w[4*i+1] + qx.z * w[4*i+2] + qx.w * w[4*i+3];
                }
                qE[(size_t)(r0 + r) * (H_ * DKE_) + hj] = f2bf(a);
            }
        }
    } else {
        const int r0 = (blockIdx.x - 128) * 8;          // global (b,m) row
        reinterpret_cast<float4*>(&Xs[0][0])[t] =
            reinterpret_cast<const float4*>(value + (size_t)r0 * D_)[t];
        __syncthreads();

        float acc[8] = {0,0,0,0,0,0,0,0};
        const float* wcol = Wv + (t >> 5) * (D_ * O_) + (t & 31);
        for (int k = 0; k < D_; k += 4) {
            const float w0 = wcol[(k+0) * O_];
            const float w1 = wcol[(k+1) * O_];
            const float w2 = wcol[(k+2) * O_];
            const float w3 = wcol[(k+3) * O_];
#pragma unroll
            for (int r = 0; r < 8; ++r) {
                const float4 x = *reinterpret_cast<const float4*>(&Xs[r][k]);
                acc[r] += x.x * w0 + x.y * w1 + x.z * w2 + x.w * w3;
            }
        }
        // transposed bf16 write: vvT[b][col=t][m0..m0+7] as one 16 B store
        const int bb = r0 >> 9, m0 = r0 & 511;
        union { u32 u[4]; uint4 q; } pk;
        pk.u[0] = pk2bf(acc[0], acc[1]);
        pk.u[1] = pk2bf(acc[2], acc[3]);
        pk.u[2] = pk2bf(acc[4], acc[5]);
        pk.u[3] = pk2bf(acc[6], acc[7]);
        *reinterpret_cast<uint4*>(vvT + (size_t)bb * 256 * M_ + (size_t)t * M_ + m0) = pk.q;
    }
}

// ---------------------------------------------------------------------------
// k_attn: per (b,n). Logits via MFMA 16x16x32 bf16 with fragments loaded
// DIRECTLY from global (no LDS staging): B row = cat(key,edge)[m], lane
// row=l&15, k=(l>>4)*8+j. Then softmax, bf16-streamed PV, projection.
// grid = 1024 x 256 (4 waves x 8 m-tiles each); 4 blocks/CU = 1 full round.
// ---------------------------------------------------------------------------
__global__ __launch_bounds__(256, 4) void k_attn(
    const float* __restrict__ key, const float* __restrict__ edge,
    const u16* __restrict__ qE, const u16* __restrict__ vvT,
    const float* __restrict__ Wp, const float* __restrict__ bias,
    float* __restrict__ out)
{
    const int idx  = blockIdx.x;          // b*N + n
    const int b    = idx >> 9;
    const int t    = threadIdx.x;
    const int lane = t & 63;
    const int wv   = t >> 6;

    __shared__ __attribute__((aligned(16))) float attn_s[H_][MP_]; // 16.5 KB
    __shared__ float mh_s[H_ * O_];
    __shared__ float part_s[2][OUT_];

    const int br = lane & 15;             // B column / m within tile; A row (head)
    const int q  = lane >> 4;             // k-quad

    // ---- A fragments: lane holds qE[row=br][kk*32 + q*8 + 0..7], rows>=8 zero
    bf16x8 afr[6];
    if (br < 8) {
        const u16* ab = qE + (size_t)idx * (H_ * DKE_) + br * DKE_;
#pragma unroll
        for (int kk = 0; kk < 6; ++kk)
            afr[kk] = *reinterpret_cast<const bf16x8*>(ab + kk * 32 + q * 8);
    } else {
#pragma unroll
        for (int kk = 0; kk < 6; ++kk) afr[kk] = bf16x8{0,0,0,0,0,0,0,0};
    }

    const float* keyb = key  + (size_t)b   * M_ * D_;
    const float* eb   = edge + (size_t)idx * M_ * DE_;

    // ---- logits: 8 m-tiles per wave, fragments straight from global ----
    for (int it = 0; it < 8; ++it) {
        const int tl = it * 4 + wv;
        const int m  = tl * 16 + br;
        const float* kr = keyb + (size_t)m * D_  + q * 8;
        const float* er = eb   + (size_t)m * DE_ + q * 8;
        float4 kf[8], ef[4];
#pragma unroll
        for (int kk = 0; kk < 4; ++kk) {
            kf[2*kk]   = *reinterpret_cast<const float4*>(kr + kk * 32);
            kf[2*kk+1] = *reinterpret_cast<const float4*>(kr + kk * 32 + 4);
        }
#pragma unroll
        for (int kk = 0; kk < 2; ++kk) {
            ef[2*kk]   = *reinterpret_cast<const float4*>(er + kk * 32);
            ef[2*kk+1] = *reinterpret_cast<const float4*>(er + kk * 32 + 4);
        }
        floatx4 acc = {0.f, 0.f, 0.f, 0.f};
#pragma unroll
        for (int kk = 0; kk < 4; ++kk)
            acc = __builtin_amdgcn_mfma_f32_16x16x32_bf16(afr[kk], cvt8(kf[2*kk], kf[2*kk+1]), acc, 0, 0, 0);
#pragma unroll
        for (int kk = 0; kk < 2; ++kk)
            acc = __builtin_amdgcn_mfma_f32_16x16x32_bf16(afr[4+kk], cvt8(ef[2*kk], ef[2*kk+1]), acc, 0, 0, 0);
        if (q < 2) {
#pragma unroll
            for (int i = 0; i < 4; ++i)
                attn_s[q * 4 + i][tl * 16 + br] = acc[i];
        }
    }
    __syncthreads();

    // ---- softmax over m per head (32 lanes own one head row) ----
    {
        const int h = t >> 5, ml = t & 31;
        float mx = -3.4e38f;
#pragma unroll 2
        for (int j = 0; j < 16; ++j) mx = fmaxf(mx, attn_s[h][ml + 32 * j]);
#pragma unroll
        for (int mask = 16; mask >= 1; mask >>= 1) mx = fmaxf(mx, __shfl_xor(mx, mask, 64));
        float sum = 0.f;
#pragma unroll 2
        for (int j = 0; j < 16; ++j) {
            const int m = ml + 32 * j;
            const float p = __expf(attn_s[h][m] - mx);
            attn_s[h][m] = p;
            sum += p;
        }
#pragma unroll
        for (int mask = 16; mask >= 1; mask >>= 1) sum += __shfl_xor(sum, mask, 64);
        const float inv = 1.f / sum;
#pragma unroll 2
        for (int j = 0; j < 16; ++j) attn_s[h][ml + 32 * j] *= inv;
    }
    __syncthreads();

    // ---- mh[h][o]: thread=(h,o)=t streams vvT[b][t][*] (contiguous bf16) ----
    {
        const int hh = t >> 5;
        const u16* vrow = vvT + (size_t)b * 256 * M_ + (size_t)t * M_;
        float a0 = 0.f, a1 = 0.f;
        for (int m0 = 0; m0 < M_; m0 += 8) {
            const bf16x8 v8 = *reinterpret_cast<const bf16x8*>(vrow + m0);
            const float4 w0 = *reinterpret_cast<const float4*>(&attn_s[hh][m0]);
            const float4 w1 = *reinterpret_cast<const float4*>(&attn_s[hh][m0 + 4]);
            a0 += w0.x * bf2f((u16)v8[0]) + w0.y * bf2f((u16)v8[1])
                + w0.z * bf2f((u16)v8[2]) + w0.w * bf2f((u16)v8[3]);
            a1 += w1.x * bf2f((u16)v8[4]) + w1.y * bf2f((u16)v8[5])
                + w1.z * bf2f((u16)v8[6]) + w1.w * bf2f((u16)v8[7]);
        }
        mh_s[t] = a0 + a1;
    }
    __syncthreads();

    // ---- out[c] = bias[c] + sum_j mh[j] * Wp[j*128 + c] ----
    {
        const int half = t >> 7;
        const int c = t & 127;
        float acc = 0.f;
        const int j0 = half * 128;
#pragma unroll 8
        for (int jj = 0; jj < 128; ++jj)
            acc += mh_s[j0 + jj] * Wp[(size_t)(j0 + jj) * OUT_ + c];
        part_s[half][c] = acc;
    }
    __syncthreads();
    if (t < OUT_)
        out[(size_t)idx * OUT_ + t] = part_s[0][t] + part_s[1][t] + bias[t];
}

// ---------------------------------------------------------------------------
extern "C" void kernel_launch(void* const* d_in, const int* in_sizes, int n_in,
                              void* d_out, int out_size, void* d_ws, size_t ws_size,
                              hipStream_t stream)
{
    const float* query = (const float*)d_in[0];   // [B,N,128]
    const float* key   = (const float*)d_in[1];   // [B,M,128]
    const float* value = (const float*)d_in[2];   // [B,M,128]
    const float* edge  = (const float*)d_in[3];   // [B,N,M,64]
    const float* Wq    = (const float*)d_in[4];   // [8,128,32]
    const float* Wk    = (const float*)d_in[5];   // [8,192,32]
    const float* Wv    = (const float*)d_in[6];   // [8,128,32]
    const float* Wp    = (const float*)d_in[7];   // [8,32,128]
    const float* bias  = (const float*)d_in[8];   // [128]
    float* out = (float*)d_out;                   // [B,N,128] fp32

    u16* qE_ws = (u16*)d_ws;                                          // 1024*1536*2 = 3.1 MB
    u16* vT_ws = (u16*)((char*)d_ws + (size_t)B_*N_*H_*DKE_*2);       // 2*256*512*2 = 512 KB

    k_proj<<<256,  256, 0, stream>>>(query, Wq, Wk, value, Wv, qE_ws, vT_ws);
    k_attn<<<1024, 256, 0, stream>>>(key, edge, qE_ws, vT_ws, Wp, bias, out);
}